// Round 9
// baseline (56.375 us; speedup 1.0000x reference)
//
#include <hip/hip_runtime.h>
#include <stdint.h>

#define NQ   12
#define DIM  4096   // 2^12 amplitudes
#define TPB  256

typedef float   v2f   __attribute__((ext_vector_type(2)));
typedef float   v4f   __attribute__((ext_vector_type(4)));
typedef float   f32x4 __attribute__((ext_vector_type(4)));
typedef _Float16 v2h  __attribute__((ext_vector_type(2)));
typedef _Float16 f16x8 __attribute__((ext_vector_type(8)));
typedef uint32_t u32x4 __attribute__((ext_vector_type(4)));

// ---------- compile-time GF(2) circuit structure ----------
struct PassP {
  uint16_t v[4];    // pair XOR-vectors (permuted order: bit i of r <-> v[i])
  uint16_t m[4];    // role parity masks (permuted to match v)
  uint16_t td[4];   // baseT deltas (B * T-bit columns)
  uint8_t  np[8];   // free-bit slots: [0..3]=j, [4..5]=T, [6..7]=wave
  uint8_t  wire[4]; // absolute wire index for r-bit i
  uint8_t  layer;   // 1 or 2
  uint8_t  pad[3];
};
struct ROC {
  uint16_t mask[12]; // rows of A^3
  uint8_t  bin[12];  // WHT bin per qubit over pass5 lane-span {v0,v3,td1,td2}
};

constexpr int chbit(uint32_t x) { int b = -1; for (int i = 0; i < 32; ++i) if ((x >> i) & 1u) b = i; return b; }

constexpr void bmm(uint32_t* C, const uint32_t* A, const uint32_t* B) {
  for (int i = 0; i < NQ; ++i) {
    uint32_t r = 0;
    for (int j = 0; j < NQ; ++j) if ((A[i] >> j) & 1u) r ^= B[j];
    C[i] = r;
  }
}
constexpr void binv(const uint32_t* M, uint32_t* Inv) {
  uint32_t A[NQ] = {}, I[NQ] = {};
  for (int i = 0; i < NQ; ++i) { A[i] = M[i]; I[i] = 1u << i; }
  for (int c = 0; c < NQ; ++c) {
    int piv = -1;
    for (int r = c; r < NQ; ++r) if ((A[r] >> c) & 1u) { piv = r; break; }
    if (piv < 0) continue;
    uint32_t ta = A[c]; A[c] = A[piv]; A[piv] = ta;
    uint32_t ti = I[c]; I[c] = I[piv]; I[piv] = ti;
    for (int r = 0; r < NQ; ++r)
      if (r != c && ((A[r] >> c) & 1u)) { A[r] ^= A[c]; I[r] ^= I[c]; }
  }
  for (int i = 0; i < NQ; ++i) Inv[i] = I[i];
}

constexpr int rank5(const uint32_t* cols, int n) {
  uint32_t rows[5] = {}; int rnk = 0;
  for (int q = 0; q < n; ++q) {
    uint32_t x = cols[q] & 31u;
    for (int bit = 4; bit >= 0; --bit) {
      if (!((x >> bit) & 1u)) continue;
      if (rows[bit]) { x ^= rows[bit]; }
      else { rows[bit] = x; ++rnk; break; }
    }
  }
  return rnk;
}
// measured LDS conflict penalty (m136)
constexpr int penalty(int r) {
  return r >= 5 ? 0 : r == 4 ? 58 : r == 3 ? 194 : r == 2 ? 469 : 1100;
}

// One pass's structure; SEPARATE constexpr evaluation per pass (step-limit lesson).
constexpr PassP make_pass(int p) {
  PassP pp{};
  uint32_t A[NQ] = {}; A[0] = 0xFFEu;
  for (int i = 1; i < NQ; ++i) A[i] = (1u << (i + 1)) - 1u;
  uint32_t A2[NQ] = {}, Ai[NQ] = {}, A2i[NQ] = {};
  bmm(A2, A, A);
  binv(A, Ai); binv(A2, A2i);

  const int L = (p < 3) ? 1 : 2;
  const int wb = (p % 3) * 4;
  const uint32_t* M  = (L == 1) ? A  : A2;
  const uint32_t* Mi = (L == 1) ? Ai : A2i;
  uint32_t v0[4] = {}, m0[4] = {};
  for (int i = 0; i < 4; ++i) {
    int w = wb + i; uint32_t col = 0;
    for (int r = 0; r < NQ; ++r) col |= ((Mi[r] >> w) & 1u) << r;
    v0[i] = col; m0[i] = M[w];
  }
  uint32_t Bc[NQ] = {};
  for (int b = 0; b < NQ; ++b) {
    uint32_t col = 1u << b;
    for (int i = 0; i < 4; ++i) if ((m0[i] >> b) & 1u) col ^= v0[i];
    Bc[b] = col;
  }
  uint32_t redv[4] = {}; int pbit[4] = {}; uint32_t pivmask = 0;
  for (int i = 0; i < 4; ++i) {
    redv[i] = v0[i];
    for (int k2 = 0; k2 < i; ++k2) if ((redv[i] >> pbit[k2]) & 1u) redv[i] ^= redv[k2];
    pbit[i] = chbit(redv[i]); pivmask |= 1u << pbit[i];
  }
  uint8_t np0[8] = {}; int nc = 0;
  for (int b = 0; b < NQ; ++b) if (!((pivmask >> b) & 1u)) np0[nc++] = (uint8_t)b;

  int bestCost = 1 << 30;
  int bsel[4] = {0, 1, 2, 3}; int bperm[4] = {0, 1, 2, 3};
  for (int a = 0; a < 8; ++a) for (int b = a + 1; b < 8; ++b)
  for (int c = b + 1; c < 8; ++c) for (int d = c + 1; d < 8; ++d) {
    uint32_t jc[4] = {Bc[np0[a]], Bc[np0[b]], Bc[np0[c]], Bc[np0[d]]};
    int prk[4][4] = {};
    for (int i = 0; i < 4; ++i)
      for (int j = i + 1; j < 4; ++j) {
        uint32_t sp[6] = {jc[0], jc[1], jc[2], jc[3], v0[i], v0[j]};
        prk[i][j] = prk[j][i] = rank5(sp, 6);
      }
    for (int pa = 0; pa < 4; ++pa) for (int pb2 = 0; pb2 < 4; ++pb2) {
      if (pb2 == pa) continue;
      for (int pc = 0; pc < 4; ++pc) {
        if (pc == pa || pc == pb2) continue;
        const int pd = 6 - pa - pb2 - pc;
        const int cost = penalty(prk[pc][pd]) + penalty(prk[pb2][pc]);
        if (cost < bestCost) {
          bestCost = cost;
          bsel[0] = a; bsel[1] = b; bsel[2] = c; bsel[3] = d;
          bperm[0] = pa; bperm[1] = pb2; bperm[2] = pc; bperm[3] = pd;
        }
      }
    }
  }
  int rem[4] = {}; int rc2 = 0;
  for (int q = 0; q < 8; ++q)
    if (q != bsel[0] && q != bsel[1] && q != bsel[2] && q != bsel[3]) rem[rc2++] = q;

  uint8_t npn[8] = {};
  npn[0] = np0[bsel[0]]; npn[1] = np0[bsel[1]];
  npn[2] = np0[bsel[2]]; npn[3] = np0[bsel[3]];
  npn[4] = np0[rem[0]]; npn[5] = np0[rem[1]];
  npn[6] = np0[rem[2]]; npn[7] = np0[rem[3]];
  for (int q = 0; q < 8; ++q) pp.np[q] = npn[q];
  for (int i = 0; i < 4; ++i) {
    pp.v[i] = (uint16_t)v0[bperm[i]];
    pp.m[i] = (uint16_t)m0[bperm[i]];
    pp.wire[i] = (uint8_t)(wb + bperm[i]);
  }
  pp.td[0] = 0;
  pp.td[1] = (uint16_t)Bc[npn[4]];
  pp.td[2] = (uint16_t)Bc[npn[5]];
  pp.td[3] = (uint16_t)(Bc[npn[4]] ^ Bc[npn[5]]);
  pp.layer = (uint8_t)L;
  return pp;
}

constexpr PassP kp0 = make_pass(0);
constexpr PassP kp1 = make_pass(1);
constexpr PassP kp2 = make_pass(2);
constexpr PassP kp3 = make_pass(3);
constexpr PassP kp4 = make_pass(4);
constexpr PassP kp5 = make_pass(5);

template<int P>
constexpr PassP pget() {
  if constexpr (P == 0) return kp0;
  else if constexpr (P == 1) return kp1;
  else if constexpr (P == 2) return kp2;
  else if constexpr (P == 3) return kp3;
  else if constexpr (P == 4) return kp4;
  else return kp5;
}

constexpr ROC make_ro() {
  ROC r{};
  uint32_t A[NQ] = {}; A[0] = 0xFFEu;
  for (int i = 1; i < NQ; ++i) A[i] = (1u << (i + 1)) - 1u;
  uint32_t A2[NQ] = {}, A3[NQ] = {};
  bmm(A2, A, A); bmm(A3, A2, A);
  for (int i = 0; i < NQ; ++i) r.mask[i] = (uint16_t)A3[i];
  for (int i = 0; i < NQ; ++i) {
    uint32_t b = 0;
    b |= (uint32_t)(__builtin_popcount(A3[i] & (uint32_t)kp5.v[0]) & 1) << 0;
    b |= (uint32_t)(__builtin_popcount(A3[i] & (uint32_t)kp5.v[3]) & 1) << 1;
    b |= (uint32_t)(__builtin_popcount(A3[i] & (uint32_t)kp5.td[1]) & 1) << 2;
    b |= (uint32_t)(__builtin_popcount(A3[i] & (uint32_t)kp5.td[2]) & 1) << 3;
    r.bin[i] = (uint8_t)b;
  }
  return r;
}
constexpr ROC roc = make_ro();

// ---------- device helpers ----------
__device__ __forceinline__ v2f cmulf(v2f a, v2f b) {
  return (v2f){a.x * b.x - a.y * b.y, a.x * b.y + a.y * b.x};
}
__device__ __forceinline__ uint32_t f2h2(float a, float b) {
  return __builtin_bit_cast(uint32_t, __builtin_amdgcn_cvt_pkrtz(a, b));
}
__device__ __forceinline__ uint32_t pk_rtn(float a, float b) {
  v2h h = {(_Float16)a, (_Float16)b};
  return __builtin_bit_cast(uint32_t, h);
}

__device__ __forceinline__ void build_u(const float* __restrict__ qp, int l, int w, float U[8]) {
  float p0 = qp[(l * 12 + w) * 3 + 0];
  float p1 = qp[(l * 12 + w) * 3 + 1];
  float p2 = qp[(l * 12 + w) * 3 + 2];
  float cx, sx, cy, sy, cz, sz;
  sincosf(0.5f * p0, &sx, &cx);
  sincosf(0.5f * p1, &sy, &cy);
  sincosf(0.5f * p2, &sz, &cz);
  float M00x =  cy * cx, M00y =  sy * sx;
  float M01x = -sy * cx, M01y = -cy * sx;
  float M10x =  sy * cx, M10y = -cy * sx;
  float M11x =  cy * cx, M11y = -sy * sx;
  U[0] = cz * M00x + sz * M00y; U[1] = cz * M00y - sz * M00x;
  U[2] = cz * M01x + sz * M01y; U[3] = cz * M01y - sz * M01x;
  U[4] = cz * M10x - sz * M10y; U[5] = cz * M10y + sz * M10x;
  U[6] = cz * M11x - sz * M11y; U[7] = cz * M11y + sz * M11x;
}

// Am column swizzle (quad-granular; kept so A-fragment index math is unchanged)
__device__ __forceinline__ int am_col(int c, int i) {
  return ((((c >> 2) ^ ((i >> 1) & 3)) << 2) | (c & 3));
}

// build one pass's real-rep f16 kron matrix entry into GLOBAL Am (prep kernel)
template<int P>
__device__ __forceinline__ void build_am_g(uint32_t* __restrict__ Am_g,
                                           const v2f (*gg)[12][4], int t) {
  constexpr PassP pp = pget<P>();
  const int r_ = t >> 4, c_ = t & 15;
  v2f e = (v2f){1.f, 0.f};
  #pragma unroll
  for (int i = 0; i < 4; ++i) {
    v2f u = gg[pp.layer - 1][pp.wire[i]][(((r_ >> i) & 1) << 1) | ((c_ >> i) & 1)];
    e = cmulf(e, u);
  }
  const int ra = 2 * r_, rb = 2 * r_ + 1;
  Am_g[P * 512 + ra * 16 + am_col(c_, ra)] = pk_rtn(e.x, -e.y);
  Am_g[P * 512 + rb * 16 + am_col(c_, rb)] = pk_rtn(e.y, e.x);
}

// ---------- prep kernel: sample-invariant data, built ONCE ----------
__global__ __launch_bounds__(256) void prep_kernel(const float* __restrict__ qp,
                                                   uint32_t* __restrict__ Am_g,
                                                   float* __restrict__ U0_g) {
  __shared__ v2f gg[2][12][4];
  const int t = threadIdx.x;
  if (t < 24) {
    const int L = t / 12 + 1, w = t % 12;
    float U[8]; build_u(qp, L, w, U);
    gg[L - 1][w][0] = (v2f){U[0], U[1]};
    gg[L - 1][w][1] = (v2f){U[2], U[3]};
    gg[L - 1][w][2] = (v2f){U[4], U[5]};
    gg[L - 1][w][3] = (v2f){U[6], U[7]};
  } else if (t >= 32 && t < 44) {
    const int w = t - 32;
    float U[8]; build_u(qp, 0, w, U);
    #pragma unroll
    for (int k = 0; k < 8; ++k) U0_g[w * 8 + k] = U[k];
  }
  __syncthreads();
  build_am_g<0>(Am_g, gg, t);
  build_am_g<1>(Am_g, gg, t);
  build_am_g<2>(Am_g, gg, t);
  build_am_g<3>(Am_g, gg, t);
  build_am_g<4>(Am_g, gg, t);
  build_am_g<5>(Am_g, gg, t);
}

// ---------- per-pass MFMA engine (A-fragments passed in registers) ----------
template<int P, bool LAST>
__device__ __forceinline__ void do_pass(uint32_t* st, f16x8 a0, f16x8 a1,
                                        int t, float* ev) {
  constexpr PassP pp = pget<P>();
  const int lane = t & 63;
  const int wv   = t >> 6;
  const int g    = lane >> 4;
  const int t6 = (lane & 15) | (wv << 6);
  int rep = 0;
  #pragma unroll
  for (int k = 0; k < 8; ++k) rep |= ((t6 >> k) & 1) << pp.np[k];
  int base = rep;
  #pragma unroll
  for (int i = 0; i < 4; ++i)
    if (__popc(pp.m[i] & rep) & 1) base ^= pp.v[i];
  const int cgr = ((g & 1) ? pp.v[2] : 0) ^ ((g & 2) ? pp.v[3] : 0);
  const int cgw = ((g & 1) ? pp.v[1] : 0) ^ ((g & 2) ? pp.v[2] : 0);
  float pr[16];
  const f32x4 z = {0.f, 0.f, 0.f, 0.f};
  #pragma unroll
  for (int T = 0; T < 4; ++T) {
    const int bT = base ^ pp.td[T];
    const int ra = bT ^ cgr;
    u32x4 braw = { st[ra], st[ra ^ pp.v[0]], st[ra ^ pp.v[1]],
                   st[ra ^ (pp.v[0] ^ pp.v[1])] };
    f16x8 bf = __builtin_bit_cast(f16x8, braw);
    f32x4 c0 = __builtin_amdgcn_mfma_f32_16x16x32_f16(a0, bf, z, 0, 0, 0);
    f32x4 c1 = __builtin_amdgcn_mfma_f32_16x16x32_f16(a1, bf, z, 0, 0, 0);
    if constexpr (!LAST) {
      const int wa = bT ^ cgw;
      st[wa]                       = f2h2(c0.x, c0.y);
      st[wa ^ pp.v[0]]             = f2h2(c0.z, c0.w);
      st[wa ^ pp.v[3]]             = f2h2(c1.x, c1.y);
      st[wa ^ (pp.v[3] ^ pp.v[0])] = f2h2(c1.z, c1.w);
    } else {
      const int nb = ((T & 1) << 2) | ((T >> 1) << 3);
      pr[nb]     = c0.x * c0.x + c0.y * c0.y;
      pr[nb | 1] = c0.z * c0.z + c0.w * c0.w;
      pr[nb | 2] = c1.x * c1.x + c1.y * c1.y;
      pr[nb | 3] = c1.z * c1.z + c1.w * c1.w;
    }
  }
  if constexpr (LAST) {
    #pragma unroll
    for (int gs = 1; gs < 16; gs <<= 1) {
      #pragma unroll
      for (int j = 0; j < 16; ++j) {
        if (j & gs) continue;
        float u = pr[j], w2 = pr[j | gs];
        pr[j] = u + w2; pr[j | gs] = u - w2;
      }
    }
    const int baseL = base ^ cgw;
    #pragma unroll
    for (int i = 0; i < NQ; ++i) {
      float h = pr[roc.bin[i]];
      int s = (__popc(roc.mask[i] & baseL) & 1) << 31;
      ev[i] = __int_as_float(__float_as_int(h) ^ s);
    }
  }
}

// A-fragment global load (L2-hot 12KB table), one pass ahead of use
#define LDA(P, A0, A1) {                                                        \
  const int li_ = lane & 15;                                                    \
  const int q_  = g ^ ((li_ >> 1) & 3);                                         \
  A0 = __builtin_bit_cast(f16x8,                                                \
      *reinterpret_cast<const u32x4*>(Am_g + (P) * 512 + li_ * 16 + q_ * 4));   \
  A1 = __builtin_bit_cast(f16x8,                                                \
      *reinterpret_cast<const u32x4*>(Am_g + (P) * 512 + (li_ + 16) * 16 + q_ * 4)); \
}

// ---------- main kernel ----------
__global__ __launch_bounds__(TPB, 8) void hqc_kernel(
    const float* __restrict__ x,  const float* __restrict__ W1, const float* __restrict__ b1,
    const float* __restrict__ W2, const float* __restrict__ b2,
    const float* __restrict__ W3, const float* __restrict__ b3,
    const float* __restrict__ P1, const float* __restrict__ c1,
    const float* __restrict__ P2, const float* __restrict__ c2,
    const float* __restrict__ P3, const float* __restrict__ c3,
    const uint32_t* __restrict__ Am_g, const float* __restrict__ U0_g,
    float* __restrict__ out)
{
  __shared__ uint32_t st[DIM];     // 16 KB packed-half2 state
  __shared__ v4f  gpk0[12][2];     // L0-folded columns {x,x,-y,y}
  __shared__ float red[4][NQ];

  const int s    = blockIdx.x;
  const int t    = threadIdx.x;
  const int lane = t & 63;
  const int wv   = t >> 6;
  const int g    = lane >> 4;

  f16x8 a0c, a1c, a0n, a1n;
  LDA(0, a0c, a1c)

  // ---- phase 0a: wave0 = MLP + L0 fold (U0 from prep); other waves idle ----
  if (wv == 0 && lane < 16) {
    float a = b1[lane];
    #pragma unroll
    for (int k = 0; k < 6; ++k) a = fmaf(W1[lane * 6 + k], x[s * 6 + k], a);
    float h1 = fmaxf(a, 0.f);
    float a2 = b2[lane];
    #pragma unroll
    for (int k = 0; k < 16; ++k) a2 = fmaf(W2[lane * 16 + k], __shfl(h1, k, 64), a2);
    float h2 = fmaxf(a2, 0.f);
    const int lw = (lane < NQ) ? lane : 0;
    float a3 = b3[lw];
    #pragma unroll
    for (int k = 0; k < 16; ++k) a3 = fmaf(W3[lw * 16 + k], __shfl(h2, k, 64), a3);
    if (lane < NQ) {
      const float* u = U0_g + lane * 8;
      float ca, sa; sincosf(0.5f * a3, &sa, &ca);
      float c0x = u[0] * ca + u[2] * sa, c0y = u[1] * ca + u[3] * sa;
      float c1x = u[4] * ca + u[6] * sa, c1y = u[5] * ca + u[7] * sa;
      gpk0[lane][0] = (v4f){c0x, c0x, -c0y, c0y};
      gpk0[lane][1] = (v4f){c1x, c1x, -c1y, c1y};
    }
  }
  __syncthreads();

  // ---- product-state init: idx = t | (j<<8) ----
  {
    v2f acc = (v2f){1.f, 0.f};
    #pragma unroll
    for (int i = 0; i < 8; ++i) {
      v4f gk = gpk0[i][(t >> i) & 1];
      acc = gk.xy * acc + gk.zw * acc.yx;
    }
    v2f l16[16];
    l16[0] = acc;
    #pragma unroll
    for (int i = 0; i < 4; ++i) {
      v4f g0 = gpk0[8 + i][0], g1 = gpk0[8 + i][1];
      #pragma unroll
      for (int j = 0; j < (1 << i); ++j) {
        v2f a = l16[j];
        l16[j | (1 << i)] = g1.xy * a + g1.zw * a.yx;
        l16[j]            = g0.xy * a + g0.zw * a.yx;
      }
    }
    #pragma unroll
    for (int j = 0; j < 16; ++j) st[t | (j << 8)] = f2h2(l16[j].x, l16[j].y);
  }
  __syncthreads();

  float ev[NQ];
  LDA(1, a0n, a1n)
  do_pass<0, false>(st, a0c, a1c, t, ev); __syncthreads();
  a0c = a0n; a1c = a1n; LDA(2, a0n, a1n)
  do_pass<1, false>(st, a0c, a1c, t, ev); __syncthreads();
  a0c = a0n; a1c = a1n; LDA(3, a0n, a1n)
  do_pass<2, false>(st, a0c, a1c, t, ev); __syncthreads();
  a0c = a0n; a1c = a1n; LDA(4, a0n, a1n)
  do_pass<3, false>(st, a0c, a1c, t, ev); __syncthreads();
  a0c = a0n; a1c = a1n; LDA(5, a0n, a1n)
  do_pass<4, false>(st, a0c, a1c, t, ev); __syncthreads();
  a0c = a0n; a1c = a1n;
  do_pass<5, true >(st, a0c, a1c, t, ev);  // fused readout

  // ---- reduce 12 evs across lanes, then waves ----
  #pragma unroll
  for (int off = 32; off >= 1; off >>= 1) {
    #pragma unroll
    for (int i = 0; i < NQ; ++i) ev[i] += __shfl_xor(ev[i], off, 64);
  }
  if (lane == 0) {
    #pragma unroll
    for (int i = 0; i < NQ; ++i) red[wv][i] = ev[i];
  }
  __syncthreads();

  // ---- post-MLP on wave 0 via shuffles ----
  if (wv == 0 && lane < 16) {
    float q = (lane < NQ)
      ? (red[0][lane] + red[1][lane] + red[2][lane] + red[3][lane])
      : 0.f;
    float a = c1[lane];
    #pragma unroll
    for (int j = 0; j < NQ; ++j) a = fmaf(P1[lane * NQ + j], __shfl(q, j, 64), a);
    float o1 = fmaxf(a, 0.f);
    float a2 = c2[lane & 7];
    #pragma unroll
    for (int j = 0; j < 16; ++j) a2 = fmaf(P2[(lane & 7) * 16 + j], __shfl(o1, j, 64), a2);
    float o2 = fmaxf(a2, 0.f);
    float a3 = c3[0];
    #pragma unroll
    for (int j = 0; j < 8; ++j) a3 = fmaf(P3[j], __shfl(o2, j, 64), a3);
    if (lane == 0) out[s] = 1.f / (1.f + expf(-a3));
  }
}

extern "C" void kernel_launch(void* const* d_in, const int* in_sizes, int n_in,
                              void* d_out, int out_size, void* d_ws, size_t ws_size,
                              hipStream_t stream) {
  (void)in_sizes; (void)n_in; (void)ws_size;
  uint32_t* Am_g = (uint32_t*)d_ws;                       // 6*512*4 = 12288 B
  float*    U0_g = (float*)((char*)d_ws + 6 * 512 * 4);   // 12*8*4  =   384 B
  const float* qp = (const float*)d_in[7];
  prep_kernel<<<1, 256, 0, stream>>>(qp, Am_g, U0_g);
  hqc_kernel<<<out_size, TPB, 0, stream>>>(
      (const float*)d_in[0],  (const float*)d_in[1],  (const float*)d_in[2],
      (const float*)d_in[3],  (const float*)d_in[4],  (const float*)d_in[5],
      (const float*)d_in[6],
      (const float*)d_in[8],  (const float*)d_in[9],
      (const float*)d_in[10], (const float*)d_in[11],
      (const float*)d_in[12], (const float*)d_in[13],
      Am_g, U0_g,
      (float*)d_out);
}

// Round 10
// 48.284 us; speedup vs baseline: 1.1676x; 1.1676x over previous
//
#include <hip/hip_runtime.h>
#include <stdint.h>

#define NQ   12
#define DIM  4096   // 2^12 amplitudes
#define TPB  256

typedef float   v2f   __attribute__((ext_vector_type(2)));
typedef float   v4f   __attribute__((ext_vector_type(4)));
typedef float   f32x4 __attribute__((ext_vector_type(4)));
typedef _Float16 v2h  __attribute__((ext_vector_type(2)));
typedef _Float16 f16x8 __attribute__((ext_vector_type(8)));
typedef uint32_t u32x4 __attribute__((ext_vector_type(4)));

// ---------- compile-time GF(2) machinery ----------
struct PassL {           // logical structure of one pass
  uint32_t v[4], m[4];   // pair vectors / role masks (slot i <-> wire wb+i)
  uint32_t Be[8];        // B * e_np[k]
  uint8_t  np[8];
  uint8_t  layer, wb;
};
struct PassC {           // device constants
  uint16_t WD[8];        // Lambda_{P+1}(B_P e_np[k]); k=0..3 n-bits, 4..5 T, 6..7 wv
  uint16_t WQ1, WQ2;     // Lambda_{P+1}(v1), (v2)   (cgw selects)
  uint16_t WV0, WV3;     // write quad deltas
  uint16_t SM[12];       // pass5: sign masks over packed lane coords
  uint8_t  robin[12];    // pass5: WHT bin per qubit
  uint8_t  layer, wb;
};
struct InitC { uint16_t ICt[8]; uint16_t ICj[16]; };

constexpr int par(uint32_t x) { return __builtin_popcount(x) & 1; }

constexpr void bmm(uint32_t* C, const uint32_t* A, const uint32_t* B) {
  for (int i = 0; i < NQ; ++i) {
    uint32_t r = 0;
    for (int j = 0; j < NQ; ++j) if ((A[i] >> j) & 1u) r ^= B[j];
    C[i] = r;
  }
}
constexpr void binv(const uint32_t* M, uint32_t* Inv) {
  uint32_t A[NQ] = {}, I[NQ] = {};
  for (int i = 0; i < NQ; ++i) { A[i] = M[i]; I[i] = 1u << i; }
  for (int c = 0; c < NQ; ++c) {
    int piv = -1;
    for (int r = c; r < NQ; ++r) if ((A[r] >> c) & 1u) { piv = r; break; }
    if (piv < 0) continue;
    uint32_t ta = A[c]; A[c] = A[piv]; A[piv] = ta;
    uint32_t ti = I[c]; I[c] = I[piv]; I[piv] = ti;
    for (int r = 0; r < NQ; ++r)
      if (r != c && ((A[r] >> c) & 1u)) { A[r] ^= A[c]; I[r] ^= I[c]; }
  }
  for (int i = 0; i < NQ; ++i) Inv[i] = I[i];
}
constexpr int rank5(const uint32_t* cols, int n) {
  uint32_t rows[5] = {}; int rnk = 0;
  for (int q = 0; q < n; ++q) {
    uint32_t x = cols[q] & 31u;
    for (int bit = 4; bit >= 0; --bit) {
      if (!((x >> bit) & 1u)) continue;
      if (rows[bit]) { x ^= rows[bit]; }
      else { rows[bit] = x; ++rnk; break; }
    }
  }
  return rnk;
}

constexpr PassL passL_default(int p) {
  PassL L{};
  uint32_t A[NQ] = {}; A[0] = 0xFFEu;
  for (int i = 1; i < NQ; ++i) A[i] = (1u << (i + 1)) - 1u;
  uint32_t A2[NQ] = {}, Ai[NQ] = {}, A2i[NQ] = {};
  bmm(A2, A, A); binv(A, Ai); binv(A2, A2i);
  const int Lr = (p < 3) ? 1 : 2, wb = (p % 3) * 4;
  const uint32_t* M  = (Lr == 1) ? A  : A2;
  const uint32_t* Mi = (Lr == 1) ? Ai : A2i;
  for (int i = 0; i < 4; ++i) {
    const int w = wb + i; uint32_t col = 0;
    for (int r = 0; r < NQ; ++r) col |= ((Mi[r] >> w) & 1u) << r;
    L.v[i] = col; L.m[i] = M[w];
  }
  uint32_t Bc[NQ] = {};
  for (int b = 0; b < NQ; ++b) {
    uint32_t col = 1u << b;
    for (int i = 0; i < 4; ++i) if ((L.m[i] >> b) & 1u) col ^= L.v[i];
    Bc[b] = col;
  }
  // pivot bits of span{v} -> 8 free bits (ascending default order)
  uint32_t redv[4] = {}; uint32_t pivmask = 0;
  for (int i = 0; i < 4; ++i) {
    redv[i] = L.v[i];
    for (int k = 0; k < i; ++k) {
      int pb = 0;
      for (int b = 0; b < NQ; ++b) if ((redv[k] >> b) & 1u) pb = b;
      if ((redv[i] >> pb) & 1u) redv[i] ^= redv[k];
    }
    int pb = 0;
    for (int b = 0; b < NQ; ++b) if ((redv[i] >> b) & 1u) pb = b;
    pivmask |= 1u << pb;
  }
  int c = 0;
  for (int b = 0; b < NQ; ++b)
    if (!((pivmask >> b) & 1u)) { L.np[c] = (uint8_t)b; L.Be[c] = Bc[b]; ++c; }
  L.layer = (uint8_t)Lr; L.wb = (uint8_t)wb;
  return L;
}

// physical layout: basis {v0,v1,v2,v3, Be0..7} -> bits {0,1,6,7, 2,3,4,5, 8,9,10,11}
constexpr uint8_t ASSIGN[12] = {0, 1, 6, 7, 2, 3, 4, 5, 8, 9, 10, 11};
struct Lam { uint32_t minv[NQ]; };
constexpr Lam make_lam(const PassL& L) {
  uint32_t bas[12] = {L.v[0], L.v[1], L.v[2], L.v[3],
                      L.Be[0], L.Be[1], L.Be[2], L.Be[3],
                      L.Be[4], L.Be[5], L.Be[6], L.Be[7]};
  uint32_t Mr[NQ] = {};
  for (int i = 0; i < NQ; ++i) {
    uint32_t r = 0;
    for (int j = 0; j < NQ; ++j) r |= ((bas[j] >> i) & 1u) << j;
    Mr[i] = r;
  }
  Lam lm{};
  binv(Mr, lm.minv);
  return lm;
}
constexpr uint32_t lap(const Lam& lm, uint32_t y) {
  uint32_t r = 0;
  for (int j = 0; j < NQ; ++j)
    if (par(lm.minv[j] & y)) r ^= 1u << ASSIGN[j];
  return r;
}

constexpr int P4[24][4] = {
  {0,1,2,3},{0,1,3,2},{0,2,1,3},{0,2,3,1},{0,3,1,2},{0,3,2,1},
  {1,0,2,3},{1,0,3,2},{1,2,0,3},{1,2,3,0},{1,3,0,2},{1,3,2,0},
  {2,0,1,3},{2,0,3,1},{2,1,0,3},{2,1,3,0},{2,3,0,1},{2,3,1,0},
  {3,0,1,2},{3,0,2,1},{3,1,0,2},{3,1,2,0},{3,2,0,1},{3,2,1,0}};

constexpr PassL reorder_np(const PassL& L, int pi, int s45, int s67) {
  PassL T = L;
  for (int k = 0; k < 4; ++k) { T.np[k] = L.np[P4[pi][k]]; T.Be[k] = L.Be[P4[pi][k]]; }
  if (s45) { T.np[4] = L.np[5]; T.np[5] = L.np[4]; T.Be[4] = L.Be[5]; T.Be[5] = L.Be[4]; }
  if (s67) { T.np[6] = L.np[7]; T.np[7] = L.np[6]; T.Be[6] = L.Be[7]; T.Be[7] = L.Be[6]; }
  return T;
}

// choose pass-p np ordering so the PREVIOUS pass's write addresses spread banks
constexpr PassL passL_ordered(int p, const PassL& prev) {
  const PassL L = passL_default(p);
  int best = -1; PassL bestL = L;
  for (int pi = 0; pi < 24; ++pi)
  for (int s45 = 0; s45 < 2; ++s45)
  for (int s67 = 0; s67 < 2; ++s67) {
    const PassL T = reorder_np(L, pi, s45, s67);
    const Lam lm = make_lam(T);
    uint32_t g[8] = { lap(lm, prev.Be[0]), lap(lm, prev.Be[1]),
                      lap(lm, prev.Be[2]), lap(lm, prev.Be[3]),
                      lap(lm, prev.v[1]),  lap(lm, prev.v[2]),
                      lap(lm, prev.Be[6]), lap(lm, prev.Be[7]) };
    const int r = rank5(g, 8);
    if (r > best) { best = r; bestL = T; }
  }
  return bestL;
}

constexpr PassL L0 = passL_default(0);
constexpr PassL L1 = passL_ordered(1, L0);
constexpr PassL L2 = passL_ordered(2, L1);
constexpr PassL L3 = passL_ordered(3, L2);
constexpr PassL L4 = passL_ordered(4, L3);
constexpr PassL L5 = passL_ordered(5, L4);

constexpr PassC make_passC(const PassL& L, const PassL& Ln) {
  PassC c{};
  const Lam lm = make_lam(Ln);
  for (int k = 0; k < 8; ++k) c.WD[k] = (uint16_t)lap(lm, L.Be[k]);
  c.WQ1 = (uint16_t)lap(lm, L.v[1]); c.WQ2 = (uint16_t)lap(lm, L.v[2]);
  c.WV0 = (uint16_t)lap(lm, L.v[0]); c.WV3 = (uint16_t)lap(lm, L.v[3]);
  c.layer = L.layer; c.wb = L.wb;
  return c;
}
constexpr PassC make_passC5(const PassL& L) {
  PassC c{};
  uint32_t A[NQ] = {}; A[0] = 0xFFEu;
  for (int i = 1; i < NQ; ++i) A[i] = (1u << (i + 1)) - 1u;
  uint32_t A2[NQ] = {}, A3[NQ] = {};
  bmm(A2, A, A); bmm(A3, A2, A);
  for (int i = 0; i < NQ; ++i) {
    uint32_t sm = 0;
    sm |= (uint32_t)par(A3[i] & L.Be[0]) << 0;
    sm |= (uint32_t)par(A3[i] & L.Be[1]) << 1;
    sm |= (uint32_t)par(A3[i] & L.Be[2]) << 2;
    sm |= (uint32_t)par(A3[i] & L.Be[3]) << 3;
    sm |= (uint32_t)par(A3[i] & L.v[1])  << 4;
    sm |= (uint32_t)par(A3[i] & L.v[2])  << 5;
    sm |= (uint32_t)par(A3[i] & L.Be[6]) << 6;
    sm |= (uint32_t)par(A3[i] & L.Be[7]) << 7;
    c.SM[i] = (uint16_t)sm;
    uint32_t b = (uint32_t)par(A3[i] & L.v[0])
               | (uint32_t)par(A3[i] & L.v[3])  << 1
               | (uint32_t)par(A3[i] & L.Be[4]) << 2
               | (uint32_t)par(A3[i] & L.Be[5]) << 3;
    c.robin[i] = (uint8_t)b;
  }
  c.layer = L.layer; c.wb = L.wb;
  return c;
}
constexpr InitC make_init(const PassL& L) {
  InitC ic{};
  const Lam lm = make_lam(L);
  for (int b = 0; b < 8; ++b) ic.ICt[b] = (uint16_t)lap(lm, 1u << b);
  uint32_t Jc[4] = {};
  for (int b = 0; b < 4; ++b) Jc[b] = lap(lm, 1u << (8 + b));
  for (int j = 0; j < 16; ++j) {
    uint32_t r = 0;
    for (int b = 0; b < 4; ++b) if ((j >> b) & 1) r ^= Jc[b];
    ic.ICj[j] = (uint16_t)r;
  }
  return ic;
}

constexpr PassC C0 = make_passC(L0, L1);
constexpr PassC C1 = make_passC(L1, L2);
constexpr PassC C2 = make_passC(L2, L3);
constexpr PassC C3 = make_passC(L3, L4);
constexpr PassC C4 = make_passC(L4, L5);
constexpr PassC C5 = make_passC5(L5);
constexpr InitC IC = make_init(L0);

template<int P> constexpr PassC cget() {
  if constexpr (P == 0) return C0;
  else if constexpr (P == 1) return C1;
  else if constexpr (P == 2) return C2;
  else if constexpr (P == 3) return C3;
  else if constexpr (P == 4) return C4;
  else return C5;
}

// ---------- device helpers ----------
__device__ __forceinline__ v2f cmulf(v2f a, v2f b) {
  return (v2f){a.x * b.x - a.y * b.y, a.x * b.y + a.y * b.x};
}
__device__ __forceinline__ uint32_t f2h2(float a, float b) {
  return __builtin_bit_cast(uint32_t, __builtin_amdgcn_cvt_pkrtz(a, b));
}
__device__ __forceinline__ uint32_t pk_rtn(float a, float b) {
  v2h h = {(_Float16)a, (_Float16)b};
  return __builtin_bit_cast(uint32_t, h);
}
__device__ __forceinline__ void build_u(const float* __restrict__ qp, int l, int w, float U[8]) {
  float p0 = qp[(l * 12 + w) * 3 + 0];
  float p1 = qp[(l * 12 + w) * 3 + 1];
  float p2 = qp[(l * 12 + w) * 3 + 2];
  float cx, sx, cy, sy, cz, sz;
  sincosf(0.5f * p0, &sx, &cx);
  sincosf(0.5f * p1, &sy, &cy);
  sincosf(0.5f * p2, &sz, &cz);
  float M00x =  cy * cx, M00y =  sy * sx;
  float M01x = -sy * cx, M01y = -cy * sx;
  float M10x =  sy * cx, M10y = -cy * sx;
  float M11x =  cy * cx, M11y = -sy * sx;
  U[0] = cz * M00x + sz * M00y; U[1] = cz * M00y - sz * M00x;
  U[2] = cz * M01x + sz * M01y; U[3] = cz * M01y - sz * M01x;
  U[4] = cz * M10x - sz * M10y; U[5] = cz * M10y + sz * M10x;
  U[6] = cz * M11x - sz * M11y; U[7] = cz * M11y + sz * M11x;
}
// Am column swizzle (global table; kept consistent between prep + LDA)
__device__ __forceinline__ int am_col(int c, int i) {
  return ((((c >> 2) ^ ((i >> 1) & 3)) << 2) | (c & 3));
}

// prep: build one pass's real-rep f16 kron matrix into global Am (1 cplx entry/thread)
template<int P>
__device__ __forceinline__ void build_am_g(uint32_t* __restrict__ Am_g,
                                           const v2f (*gg)[12][4], int t) {
  constexpr PassC pc = cget<P>();
  const int r_ = t >> 4, c_ = t & 15;
  v2f e = (v2f){1.f, 0.f};
  #pragma unroll
  for (int i = 0; i < 4; ++i) {
    v2f u = gg[pc.layer - 1][pc.wb + i][(((r_ >> i) & 1) << 1) | ((c_ >> i) & 1)];
    e = cmulf(e, u);
  }
  const int ra = 2 * r_, rb = 2 * r_ + 1;
  Am_g[P * 512 + ra * 16 + am_col(c_, ra)] = pk_rtn(e.x, -e.y);
  Am_g[P * 512 + rb * 16 + am_col(c_, rb)] = pk_rtn(e.y, e.x);
}

__global__ __launch_bounds__(256) void prep_kernel(const float* __restrict__ qp,
                                                   uint32_t* __restrict__ Am_g,
                                                   float* __restrict__ U0_g) {
  __shared__ v2f gg[2][12][4];
  const int t = threadIdx.x;
  if (t < 24) {
    const int L = t / 12 + 1, w = t % 12;
    float U[8]; build_u(qp, L, w, U);
    gg[L - 1][w][0] = (v2f){U[0], U[1]};
    gg[L - 1][w][1] = (v2f){U[2], U[3]};
    gg[L - 1][w][2] = (v2f){U[4], U[5]};
    gg[L - 1][w][3] = (v2f){U[6], U[7]};
  } else if (t >= 32 && t < 44) {
    const int w = t - 32;
    float U[8]; build_u(qp, 0, w, U);
    #pragma unroll
    for (int k = 0; k < 8; ++k) U0_g[w * 8 + k] = U[k];
  }
  __syncthreads();
  build_am_g<0>(Am_g, gg, t);
  build_am_g<1>(Am_g, gg, t);
  build_am_g<2>(Am_g, gg, t);
  build_am_g<3>(Am_g, gg, t);
  build_am_g<4>(Am_g, gg, t);
  build_am_g<5>(Am_g, gg, t);
}

// ---------- per-pass MFMA engine: strided b128 reads, scattered b32 writes ----------
template<int P, bool LAST>
__device__ __forceinline__ void do_pass(uint32_t* st, f16x8 a0, f16x8 a1,
                                        int t, float* ev) {
  constexpr PassC pc = cget<P>();
  const int lane = t & 63, wv = t >> 6;
  const int n = lane & 15, q = lane >> 4;
  const int rb = (n << 2) | (q << 6) | (wv << 10);   // trivial read base
  int wb_ = 0;
  if constexpr (!LAST) {
    wb_ = ((n & 1) ? pc.WD[0] : 0) ^ ((n & 2) ? pc.WD[1] : 0)
        ^ ((n & 4) ? pc.WD[2] : 0) ^ ((n & 8) ? pc.WD[3] : 0)
        ^ ((q & 1) ? pc.WQ1 : 0)   ^ ((q & 2) ? pc.WQ2 : 0)
        ^ ((wv & 1) ? pc.WD[6] : 0) ^ ((wv & 2) ? pc.WD[7] : 0);
  }
  float pr[16];
  const f32x4 z = {0.f, 0.f, 0.f, 0.f};
  #pragma unroll
  for (int T = 0; T < 4; ++T) {
    u32x4 braw = *reinterpret_cast<const u32x4*>(&st[rb + (T << 8)]);  // ds_read_b128
    f16x8 bf = __builtin_bit_cast(f16x8, braw);
    f32x4 c0 = __builtin_amdgcn_mfma_f32_16x16x32_f16(a0, bf, z, 0, 0, 0);
    f32x4 c1 = __builtin_amdgcn_mfma_f32_16x16x32_f16(a1, bf, z, 0, 0, 0);
    if constexpr (!LAST) {
      const int wa = wb_ ^ ((T & 1) ? pc.WD[4] : 0) ^ ((T & 2) ? pc.WD[5] : 0);
      st[wa]                       = f2h2(c0.x, c0.y);
      st[wa ^ pc.WV0]              = f2h2(c0.z, c0.w);
      st[wa ^ pc.WV3]              = f2h2(c1.x, c1.y);
      st[wa ^ (pc.WV0 ^ pc.WV3)]   = f2h2(c1.z, c1.w);
    } else {
      const int nb = ((T & 1) << 2) | ((T >> 1) << 3);
      pr[nb]     = c0.x * c0.x + c0.y * c0.y;
      pr[nb | 1] = c0.z * c0.z + c0.w * c0.w;
      pr[nb | 2] = c1.x * c1.x + c1.y * c1.y;
      pr[nb | 3] = c1.z * c1.z + c1.w * c1.w;
    }
  }
  if constexpr (LAST) {
    #pragma unroll
    for (int gs = 1; gs < 16; gs <<= 1) {
      #pragma unroll
      for (int j = 0; j < 16; ++j) {
        if (j & gs) continue;
        float u = pr[j], w2 = pr[j | gs];
        pr[j] = u + w2; pr[j | gs] = u - w2;
      }
    }
    const int pw = n | (q << 4) | (wv << 6);
    #pragma unroll
    for (int i = 0; i < NQ; ++i) {
      float h = pr[pc.robin[i]];
      int s = (__popc(pc.SM[i] & pw) & 1) << 31;
      ev[i] = __int_as_float(__float_as_int(h) ^ s);
    }
  }
}

// A-fragment global load (L2-hot 12KB table), one pass ahead of use
#define LDA(P, A0, A1) {                                                        \
  const int li_ = lane & 15;                                                    \
  const int q_  = (lane >> 4) ^ ((li_ >> 1) & 3);                               \
  A0 = __builtin_bit_cast(f16x8,                                                \
      *reinterpret_cast<const u32x4*>(Am_g + (P) * 512 + li_ * 16 + q_ * 4));   \
  A1 = __builtin_bit_cast(f16x8,                                                \
      *reinterpret_cast<const u32x4*>(Am_g + (P) * 512 + (li_ + 16) * 16 + q_ * 4)); \
}

// ---------- main kernel ----------
__global__ __launch_bounds__(TPB, 8) void hqc_kernel(
    const float* __restrict__ x,  const float* __restrict__ W1, const float* __restrict__ b1,
    const float* __restrict__ W2, const float* __restrict__ b2,
    const float* __restrict__ W3, const float* __restrict__ b3,
    const float* __restrict__ P1, const float* __restrict__ c1,
    const float* __restrict__ P2, const float* __restrict__ c2,
    const float* __restrict__ P3, const float* __restrict__ c3,
    const uint32_t* __restrict__ Am_g, const float* __restrict__ U0_g,
    float* __restrict__ out)
{
  __shared__ __align__(16) uint32_t st[DIM];   // 16 KB packed-half2 state
  __shared__ v4f  gpk0[12][2];
  __shared__ float red[4][NQ];

  const int s    = blockIdx.x;
  const int t    = threadIdx.x;
  const int lane = t & 63;
  const int wv   = t >> 6;

  f16x8 a0c, a1c, a0n, a1n;
  LDA(0, a0c, a1c)

  // ---- wave0: MLP + L0 fold; others idle (one barrier) ----
  if (wv == 0 && lane < 16) {
    float a = b1[lane];
    #pragma unroll
    for (int k = 0; k < 6; ++k) a = fmaf(W1[lane * 6 + k], x[s * 6 + k], a);
    float h1 = fmaxf(a, 0.f);
    float a2 = b2[lane];
    #pragma unroll
    for (int k = 0; k < 16; ++k) a2 = fmaf(W2[lane * 16 + k], __shfl(h1, k, 64), a2);
    float h2 = fmaxf(a2, 0.f);
    const int lw = (lane < NQ) ? lane : 0;
    float a3 = b3[lw];
    #pragma unroll
    for (int k = 0; k < 16; ++k) a3 = fmaf(W3[lw * 16 + k], __shfl(h2, k, 64), a3);
    if (lane < NQ) {
      const float* u = U0_g + lane * 8;
      float ca, sa; sincosf(0.5f * a3, &sa, &ca);
      float c0x = u[0] * ca + u[2] * sa, c0y = u[1] * ca + u[3] * sa;
      float c1x = u[4] * ca + u[6] * sa, c1y = u[5] * ca + u[7] * sa;
      gpk0[lane][0] = (v4f){c0x, c0x, -c0y, c0y};
      gpk0[lane][1] = (v4f){c1x, c1x, -c1y, c1y};
    }
  }
  __syncthreads();

  // ---- product-state init, written directly in Lambda_0 layout ----
  {
    int tb = 0;
    #pragma unroll
    for (int b = 0; b < 8; ++b) if ((t >> b) & 1) tb ^= IC.ICt[b];
    v2f acc = (v2f){1.f, 0.f};
    #pragma unroll
    for (int i = 0; i < 8; ++i) {
      v4f gk = gpk0[i][(t >> i) & 1];
      acc = gk.xy * acc + gk.zw * acc.yx;
    }
    v2f l16[16];
    l16[0] = acc;
    #pragma unroll
    for (int i = 0; i < 4; ++i) {
      v4f g0 = gpk0[8 + i][0], g1 = gpk0[8 + i][1];
      #pragma unroll
      for (int j = 0; j < (1 << i); ++j) {
        v2f a = l16[j];
        l16[j | (1 << i)] = g1.xy * a + g1.zw * a.yx;
        l16[j]            = g0.xy * a + g0.zw * a.yx;
      }
    }
    #pragma unroll
    for (int j = 0; j < 16; ++j) st[tb ^ IC.ICj[j]] = f2h2(l16[j].x, l16[j].y);
  }
  __syncthreads();

  float ev[NQ];
  LDA(1, a0n, a1n)
  do_pass<0, false>(st, a0c, a1c, t, ev); __syncthreads();
  a0c = a0n; a1c = a1n; LDA(2, a0n, a1n)
  do_pass<1, false>(st, a0c, a1c, t, ev); __syncthreads();
  a0c = a0n; a1c = a1n; LDA(3, a0n, a1n)
  do_pass<2, false>(st, a0c, a1c, t, ev); __syncthreads();
  a0c = a0n; a1c = a1n; LDA(4, a0n, a1n)
  do_pass<3, false>(st, a0c, a1c, t, ev); __syncthreads();
  a0c = a0n; a1c = a1n; LDA(5, a0n, a1n)
  do_pass<4, false>(st, a0c, a1c, t, ev); __syncthreads();
  a0c = a0n; a1c = a1n;
  do_pass<5, true >(st, a0c, a1c, t, ev);  // fused readout

  // ---- reduce across lanes, then waves ----
  #pragma unroll
  for (int off = 32; off >= 1; off >>= 1) {
    #pragma unroll
    for (int i = 0; i < NQ; ++i) ev[i] += __shfl_xor(ev[i], off, 64);
  }
  if (lane == 0) {
    #pragma unroll
    for (int i = 0; i < NQ; ++i) red[wv][i] = ev[i];
  }
  __syncthreads();

  // ---- post-MLP on wave 0 via shuffles ----
  if (wv == 0 && lane < 16) {
    float q = (lane < NQ)
      ? (red[0][lane] + red[1][lane] + red[2][lane] + red[3][lane])
      : 0.f;
    float a = c1[lane];
    #pragma unroll
    for (int j = 0; j < NQ; ++j) a = fmaf(P1[lane * NQ + j], __shfl(q, j, 64), a);
    float o1 = fmaxf(a, 0.f);
    float a2 = c2[lane & 7];
    #pragma unroll
    for (int j = 0; j < 16; ++j) a2 = fmaf(P2[(lane & 7) * 16 + j], __shfl(o1, j, 64), a2);
    float o2 = fmaxf(a2, 0.f);
    float a3 = c3[0];
    #pragma unroll
    for (int j = 0; j < 8; ++j) a3 = fmaf(P3[j], __shfl(o2, j, 64), a3);
    if (lane == 0) out[s] = 1.f / (1.f + expf(-a3));
  }
}

extern "C" void kernel_launch(void* const* d_in, const int* in_sizes, int n_in,
                              void* d_out, int out_size, void* d_ws, size_t ws_size,
                              hipStream_t stream) {
  (void)in_sizes; (void)n_in; (void)ws_size;
  uint32_t* Am_g = (uint32_t*)d_ws;                       // 6*512*4 = 12288 B
  float*    U0_g = (float*)((char*)d_ws + 6 * 512 * 4);   // 12*8*4  =   384 B
  const float* qp = (const float*)d_in[7];
  prep_kernel<<<1, 256, 0, stream>>>(qp, Am_g, U0_g);
  hqc_kernel<<<out_size, TPB, 0, stream>>>(
      (const float*)d_in[0],  (const float*)d_in[1],  (const float*)d_in[2],
      (const float*)d_in[3],  (const float*)d_in[4],  (const float*)d_in[5],
      (const float*)d_in[6],
      (const float*)d_in[8],  (const float*)d_in[9],
      (const float*)d_in[10], (const float*)d_in[11],
      (const float*)d_in[12], (const float*)d_in[13],
      Am_g, U0_g,
      (float*)d_out);
}